// Round 6
// baseline (151.804 us; speedup 1.0000x reference)
//
#include <hip/hip_runtime.h>
#include <math.h>

#define NN 50000
#define DEG 32
#define FDIM 128
#define NCLS 16
#define LN_EPS 1e-5f
#define CLAMP_MIN 1e-5f

#define PRED_NB 196              // ceil(NN/256)
#define CONV_NB 512
#define NGROUPS (NN * FDIM / 8)  // 800000 groups of 8 floats
#define FEAT_NB ((NN * 8 + 255) / 256)  // 1563

// native vector types (HIP float4 is a class — rejected by nontemporal builtins)
typedef float  nf4 __attribute__((ext_vector_type(4)));
typedef unsigned nu4 __attribute__((ext_vector_type(4)));

__device__ inline unsigned bf_rne(float x) {
    unsigned u = __float_as_uint(x);
    u += 0x7fffu + ((u >> 16) & 1u);  // round-to-nearest-even
    return u >> 16;
}

// ---------------- Kernel 1: fused  argmax(logits) (as u8)  +  h->bf16 pack ----------
__global__ __launch_bounds__(256) void k_pre(const float* __restrict__ logits,
                                             unsigned char* __restrict__ pred8,
                                             const float* __restrict__ h,
                                             unsigned* __restrict__ hb) {
    int b = blockIdx.x;
    if (b < PRED_NB) {
        int i = b * 256 + threadIdx.x;
        if (i >= NN) return;
        const nf4* lp = (const nf4*)(logits + (long)i * NCLS);
        float best = -INFINITY;
        int bi = 0;
#pragma unroll
        for (int q = 0; q < 4; ++q) {
            nf4 v = __builtin_nontemporal_load(lp + q);
#pragma unroll
            for (int r = 0; r < 4; ++r) {
                // strict > keeps FIRST max index (matches jnp.argmax)
                if (v[r] > best) { best = v[r]; bi = q * 4 + r; }
            }
        }
        pred8[i] = (unsigned char)bi;
    } else {
        int g0 = (b - PRED_NB) * 256 + threadIdx.x;
        for (int g = g0; g < NGROUPS; g += CONV_NB * 256) {
            const nf4* src = (const nf4*)(h + (long)g * 8);
            nf4 a = __builtin_nontemporal_load(src);
            nf4 c = __builtin_nontemporal_load(src + 1);
            nu4 o;
            o.x = bf_rne(a.x) | (bf_rne(a.y) << 16);
            o.y = bf_rne(a.z) | (bf_rne(a.w) << 16);
            o.z = bf_rne(c.x) | (bf_rne(c.y) << 16);
            o.w = bf_rne(c.z) | (bf_rne(c.w) << 16);
            ((nu4*)hb)[g] = o;
        }
    }
}

// ---------------- Kernel 2: f1/f2, 8 threads per node, per-block partials (NO atomics)
__global__ __launch_bounds__(256) void k_feats8(const int* __restrict__ nbr,
                                                const unsigned char* __restrict__ pred8,
                                                float* __restrict__ f1,
                                                float* __restrict__ f2,
                                                float* __restrict__ partials, int n) {
    int g = blockIdx.x * 256 + threadIdx.x;
    int node = g >> 3;
    int sub = g & 7;
    bool valid = (node < n);
    // partial histogram of 4 neighbor preds, packed 8 bits/class in two u64s
    unsigned long long lo = 0ull, hi = 0ull;
    if (valid) {
        int4 k4 = ((const int4*)(nbr + (long)node * DEG))[sub];
        int ks[4] = {k4.x, k4.y, k4.z, k4.w};
#pragma unroll
        for (int r = 0; r < 4; ++r) {
            int p = pred8[ks[r]];
            unsigned long long inc = 1ull << ((p & 7) * 8);
            if (p < 8) lo += inc; else hi += inc;
        }
    }
    // merge the 8 partial histograms within each aligned 8-lane group
#pragma unroll
    for (int m = 1; m <= 4; m <<= 1) {
        lo += __shfl_xor(lo, m);
        hi += __shfl_xor(hi, m);
    }
    float v1 = 0.f, v2 = 0.f;
    if (valid && sub == 0) {
        int cp = pred8[node];
        unsigned long long src = (cp < 8) ? lo : hi;
        v1 = (float)((src >> ((cp & 7) * 8)) & 0xffull);  // f1 = hist[center_pred]
        float ent = 0.f;
#pragma unroll
        for (int c = 0; c < NCLS; ++c) {
            unsigned long long s = (c < 8) ? lo : hi;
            float cnt = (float)((s >> ((c & 7) * 8)) & 0xffull);
            float x = fmaxf(cnt, CLAMP_MIN);  // clipped zeros contribute too
            ent -= x * logf(x);
        }
        v2 = ent;
        f1[node] = v1;
        f2[node] = v2;
    }
    // {sum f1, sum f1^2, sum f2, sum f2^2}: only sub==0 lanes carry nonzero values
    float s0 = v1, s1 = v1 * v1, s2 = v2, s3 = v2 * v2;
#pragma unroll
    for (int off = 8; off <= 32; off <<= 1) {
        s0 += __shfl_down(s0, off);
        s1 += __shfl_down(s1, off);
        s2 += __shfl_down(s2, off);
        s3 += __shfl_down(s3, off);
    }
    __shared__ float red[4][4];
    int wid = threadIdx.x >> 6;
    if ((threadIdx.x & 63) == 0) {
        red[wid][0] = s0; red[wid][1] = s1; red[wid][2] = s2; red[wid][3] = s3;
    }
    __syncthreads();
    if (threadIdx.x == 0) {
        float t0 = 0.f, t1 = 0.f, t2 = 0.f, t3 = 0.f;
#pragma unroll
        for (int w = 0; w < 4; ++w) {
            t0 += red[w][0]; t1 += red[w][1]; t2 += red[w][2]; t3 += red[w][3];
        }
        float* pp = partials + (long)blockIdx.x * 4;
        pp[0] = t0; pp[1] = t1; pp[2] = t2; pp[3] = t3;
    }
}

// ---------------- Kernel 3: finalize LayerNorm params (1 block) ----------------
__global__ __launch_bounds__(256) void k_params(const float* __restrict__ partials,
                                                int nb, float* __restrict__ params) {
    double s0 = 0, s1 = 0, s2 = 0, s3 = 0;
    for (int b = threadIdx.x; b < nb; b += 256) {
        const float* pp = partials + (long)b * 4;
        s0 += (double)pp[0]; s1 += (double)pp[1];
        s2 += (double)pp[2]; s3 += (double)pp[3];
    }
#pragma unroll
    for (int off = 32; off > 0; off >>= 1) {
        s0 += __shfl_down(s0, off);
        s1 += __shfl_down(s1, off);
        s2 += __shfl_down(s2, off);
        s3 += __shfl_down(s3, off);
    }
    __shared__ double red[4][4];
    int wid = threadIdx.x >> 6;
    if ((threadIdx.x & 63) == 0) {
        red[wid][0] = s0; red[wid][1] = s1; red[wid][2] = s2; red[wid][3] = s3;
    }
    __syncthreads();
    if (threadIdx.x == 0) {
        double t0 = 0, t1 = 0, t2 = 0, t3 = 0;
        for (int w = 0; w < 4; ++w) {
            t0 += red[w][0]; t1 += red[w][1]; t2 += red[w][2]; t3 += red[w][3];
        }
        double inv_n = 1.0 / (double)NN;
        double m1 = t0 * inv_n;
        double var1 = t1 * inv_n - m1 * m1;  // biased var, matches jnp.var
        double m2 = t2 * inv_n;
        double var2 = t3 * inv_n - m2 * m2;
        params[0] = (float)m1;
        params[1] = (float)(1.0 / sqrt(var1 + (double)LN_EPS));
        params[2] = (float)m2;
        params[3] = (float)(1.0 / sqrt(var2 + (double)LN_EPS));
    }
}

// ---------------- Kernel 4 (bf16 gather): z/gate + neighbor aggregation ----------------
// 32 lanes/node, lane = one uint2 (4 bf16) -> contiguous 256B row per gather.
// R6: 8-deep explicit load staging (MLP) + nontemporal on streaming traffic
// (nbr/h/out) so the hot 12.8MB hb table keeps the per-XCD L2.
__global__ __launch_bounds__(256) void k_agg_bf(const float* __restrict__ h,
                                                const unsigned* __restrict__ hb,
                                                const int* __restrict__ nbr,
                                                const float* __restrict__ old_z,
                                                const float* __restrict__ tau1,
                                                const float* __restrict__ tau2,
                                                const float* __restrict__ f1,
                                                const float* __restrict__ f2,
                                                const float* __restrict__ params,
                                                float* __restrict__ out_h,
                                                float* __restrict__ out_z, int n) {
    int t = blockIdx.x * 256 + threadIdx.x;
    int node = t >> 5;
    int lane = threadIdx.x & 31;
    if (node >= n) return;
    int k = __builtin_nontemporal_load(nbr + (long)node * DEG + lane);
    float4 acc = make_float4(0.f, 0.f, 0.f, 0.f);
#pragma unroll
    for (int jj = 0; jj < 4; ++jj) {
        uint2 vs[8];
#pragma unroll
        for (int j = 0; j < 8; ++j) {
            int kj = __shfl(k, jj * 8 + j, 32);
            vs[j] = ((const uint2*)(hb + (long)kj * (FDIM / 2)))[lane];
        }
#pragma unroll
        for (int j = 0; j < 8; ++j) {
            acc.x += __uint_as_float(vs[j].x << 16);
            acc.y += __uint_as_float(vs[j].x & 0xffff0000u);
            acc.z += __uint_as_float(vs[j].y << 16);
            acc.w += __uint_as_float(vs[j].y & 0xffff0000u);
        }
    }
    float a = (f1[node] - params[0]) * params[1] - tau1[0];
    float b = (f2[node] - params[2]) * params[3] - tau2[0];
    // sigmoid(-a)*sigmoid(-b) = 1 / ((1+e^a)(1+e^b))
    float z = 1.f / ((1.f + expf(a)) * (1.f + expf(b)));
    float gate = fminf(old_z[node], z);
    nf4 hv = __builtin_nontemporal_load((const nf4*)(h + (long)node * FDIM) + lane);
    nf4 o;
    o.x = hv.x + gate * fmaxf(acc.x, 0.f);
    o.y = hv.y + gate * fmaxf(acc.y, 0.f);
    o.z = hv.z + gate * fmaxf(acc.z, 0.f);
    o.w = hv.w + gate * fmaxf(acc.w, 0.f);
    __builtin_nontemporal_store(o, (nf4*)(out_h + (long)node * FDIM) + lane);
    if (lane == 0) __builtin_nontemporal_store(z, out_z + node);
}

extern "C" void kernel_launch(void* const* d_in, const int* in_sizes, int n_in,
                              void* d_out, int out_size, void* d_ws, size_t ws_size,
                              hipStream_t stream) {
    const float* h      = (const float*)d_in[0];
    const float* logits = (const float*)d_in[1];
    const float* old_z  = (const float*)d_in[2];
    const float* tau1   = (const float*)d_in[3];
    const float* tau2   = (const float*)d_in[4];
    const int*   nbr    = (const int*)d_in[5];

    // workspace layout (~13.3 MB)
    char* ws = (char*)d_ws;
    float*         params   = (float*)ws;                  // 4 floats
    float*         partials = (float*)(ws + 64);           // FEAT_NB*4 floats (~25 KB)
    unsigned char* pred8    = (unsigned char*)(ws + 32768); // NN bytes (50 KB)
    float*         f1       = (float*)(ws + 90112);        // NN floats (200 KB)
    float*         f2       = (float*)(ws + 294912);       // NN floats (200 KB)
    unsigned*      hb       = (unsigned*)(ws + 524288);    // NN*FDIM bf16 = 12.8 MB

    float* out_h = (float*)d_out;
    float* out_z = out_h + (long)NN * FDIM;

    k_pre   <<<PRED_NB + CONV_NB, 256, 0, stream>>>(logits, pred8, h, hb);
    k_feats8<<<FEAT_NB, 256, 0, stream>>>(nbr, pred8, f1, f2, partials, NN);
    k_params<<<1, 256, 0, stream>>>(partials, FEAT_NB, params);
    k_agg_bf<<<(NN * DEG + 255) / 256, 256, 0, stream>>>(h, hb, nbr, old_z, tau1, tau2,
                                                         f1, f2, params, out_h, out_z, NN);
}

// Round 7
// 148.652 us; speedup vs baseline: 1.0212x; 1.0212x over previous
//
#include <hip/hip_runtime.h>
#include <math.h>

#define NN 50000
#define DEG 32
#define FDIM 128
#define NCLS 16
#define LN_EPS 1e-5f
#define CLAMP_MIN 1e-5f

#define PRED_NB 196              // ceil(NN/256)
#define CONV_NB 512
#define NGROUPS (NN * FDIM / 8)  // 800000 groups of 8 floats
#define FEAT_NB ((NN * 8 + 255) / 256)  // 1563

// native vector types (HIP float4 is a class — rejected by nontemporal builtins)
typedef float  nf4 __attribute__((ext_vector_type(4)));
typedef unsigned nu4 __attribute__((ext_vector_type(4)));

__device__ inline unsigned bf_rne(float x) {
    unsigned u = __float_as_uint(x);
    u += 0x7fffu + ((u >> 16) & 1u);  // round-to-nearest-even
    return u >> 16;
}

// ---------------- Kernel 1: fused  argmax(logits) (as u8)  +  h->bf16 pack ----------
__global__ __launch_bounds__(256) void k_pre(const float* __restrict__ logits,
                                             unsigned char* __restrict__ pred8,
                                             const float* __restrict__ h,
                                             unsigned* __restrict__ hb) {
    int b = blockIdx.x;
    if (b < PRED_NB) {
        int i = b * 256 + threadIdx.x;
        if (i >= NN) return;
        const nf4* lp = (const nf4*)(logits + (long)i * NCLS);
        float best = -INFINITY;
        int bi = 0;
#pragma unroll
        for (int q = 0; q < 4; ++q) {
            nf4 v = __builtin_nontemporal_load(lp + q);
#pragma unroll
            for (int r = 0; r < 4; ++r) {
                // strict > keeps FIRST max index (matches jnp.argmax)
                if (v[r] > best) { best = v[r]; bi = q * 4 + r; }
            }
        }
        pred8[i] = (unsigned char)bi;
    } else {
        int g0 = (b - PRED_NB) * 256 + threadIdx.x;
        for (int g = g0; g < NGROUPS; g += CONV_NB * 256) {
            const nf4* src = (const nf4*)(h + (long)g * 8);
            nf4 a = __builtin_nontemporal_load(src);
            nf4 c = __builtin_nontemporal_load(src + 1);
            nu4 o;
            o.x = bf_rne(a.x) | (bf_rne(a.y) << 16);
            o.y = bf_rne(a.z) | (bf_rne(a.w) << 16);
            o.z = bf_rne(c.x) | (bf_rne(c.y) << 16);
            o.w = bf_rne(c.z) | (bf_rne(c.w) << 16);
            ((nu4*)hb)[g] = o;  // plain store: hb is the hot table, keep it in L2
        }
    }
}

// ---------------- Kernel 2: f1/f2, 8 threads per node, per-block partials (NO atomics)
__global__ __launch_bounds__(256) void k_feats8(const int* __restrict__ nbr,
                                                const unsigned char* __restrict__ pred8,
                                                float* __restrict__ f1,
                                                float* __restrict__ f2,
                                                float* __restrict__ partials, int n) {
    int g = blockIdx.x * 256 + threadIdx.x;
    int node = g >> 3;
    int sub = g & 7;
    bool valid = (node < n);
    // partial histogram of 4 neighbor preds, packed 8 bits/class in two u64s
    unsigned long long lo = 0ull, hi = 0ull;
    if (valid) {
        int4 k4 = ((const int4*)(nbr + (long)node * DEG))[sub];
        int ks[4] = {k4.x, k4.y, k4.z, k4.w};
#pragma unroll
        for (int r = 0; r < 4; ++r) {
            int p = pred8[ks[r]];
            unsigned long long inc = 1ull << ((p & 7) * 8);
            if (p < 8) lo += inc; else hi += inc;
        }
    }
    // merge the 8 partial histograms within each aligned 8-lane group
#pragma unroll
    for (int m = 1; m <= 4; m <<= 1) {
        lo += __shfl_xor(lo, m);
        hi += __shfl_xor(hi, m);
    }
    float v1 = 0.f, v2 = 0.f;
    if (valid && sub == 0) {
        int cp = pred8[node];
        unsigned long long src = (cp < 8) ? lo : hi;
        v1 = (float)((src >> ((cp & 7) * 8)) & 0xffull);  // f1 = hist[center_pred]
        float ent = 0.f;
#pragma unroll
        for (int c = 0; c < NCLS; ++c) {
            unsigned long long s = (c < 8) ? lo : hi;
            float cnt = (float)((s >> ((c & 7) * 8)) & 0xffull);
            float x = fmaxf(cnt, CLAMP_MIN);  // clipped zeros contribute too
            ent -= x * logf(x);
        }
        v2 = ent;
        f1[node] = v1;
        f2[node] = v2;
    }
    // {sum f1, sum f1^2, sum f2, sum f2^2}: only sub==0 lanes carry nonzero values
    float s0 = v1, s1 = v1 * v1, s2 = v2, s3 = v2 * v2;
#pragma unroll
    for (int off = 8; off <= 32; off <<= 1) {
        s0 += __shfl_down(s0, off);
        s1 += __shfl_down(s1, off);
        s2 += __shfl_down(s2, off);
        s3 += __shfl_down(s3, off);
    }
    __shared__ float red[4][4];
    int wid = threadIdx.x >> 6;
    if ((threadIdx.x & 63) == 0) {
        red[wid][0] = s0; red[wid][1] = s1; red[wid][2] = s2; red[wid][3] = s3;
    }
    __syncthreads();
    if (threadIdx.x == 0) {
        float t0 = 0.f, t1 = 0.f, t2 = 0.f, t3 = 0.f;
#pragma unroll
        for (int w = 0; w < 4; ++w) {
            t0 += red[w][0]; t1 += red[w][1]; t2 += red[w][2]; t3 += red[w][3];
        }
        float* pp = partials + (long)blockIdx.x * 4;
        pp[0] = t0; pp[1] = t1; pp[2] = t2; pp[3] = t3;
    }
}

// ---------------- Kernel 3: finalize LayerNorm params (1 block) ----------------
__global__ __launch_bounds__(256) void k_params(const float* __restrict__ partials,
                                                int nb, float* __restrict__ params) {
    double s0 = 0, s1 = 0, s2 = 0, s3 = 0;
    for (int b = threadIdx.x; b < nb; b += 256) {
        const float* pp = partials + (long)b * 4;
        s0 += (double)pp[0]; s1 += (double)pp[1];
        s2 += (double)pp[2]; s3 += (double)pp[3];
    }
#pragma unroll
    for (int off = 32; off > 0; off >>= 1) {
        s0 += __shfl_down(s0, off);
        s1 += __shfl_down(s1, off);
        s2 += __shfl_down(s2, off);
        s3 += __shfl_down(s3, off);
    }
    __shared__ double red[4][4];
    int wid = threadIdx.x >> 6;
    if ((threadIdx.x & 63) == 0) {
        red[wid][0] = s0; red[wid][1] = s1; red[wid][2] = s2; red[wid][3] = s3;
    }
    __syncthreads();
    if (threadIdx.x == 0) {
        double t0 = 0, t1 = 0, t2 = 0, t3 = 0;
        for (int w = 0; w < 4; ++w) {
            t0 += red[w][0]; t1 += red[w][1]; t2 += red[w][2]; t3 += red[w][3];
        }
        double inv_n = 1.0 / (double)NN;
        double m1 = t0 * inv_n;
        double var1 = t1 * inv_n - m1 * m1;  // biased var, matches jnp.var
        double m2 = t2 * inv_n;
        double var2 = t3 * inv_n - m2 * m2;
        params[0] = (float)m1;
        params[1] = (float)(1.0 / sqrt(var1 + (double)LN_EPS));
        params[2] = (float)m2;
        params[3] = (float)(1.0 / sqrt(var2 + (double)LN_EPS));
    }
}

// ---------------- Kernel 4 (bf16 gather): z/gate + neighbor aggregation ----------------
// 32 lanes/node, lane = one uint2 (4 bf16) -> contiguous 256B row per gather.
// R7: identity term also read from the bf16 table (hb is L2-hot), removing the
// 25.6 MB fp32 h read from the miss path. Traffic model: time ∝ TCC-miss bytes
// at ~3.7 TB/s (R1→R2 scaling evidence).
__global__ __launch_bounds__(256) void k_agg_bf(const unsigned* __restrict__ hb,
                                                const int* __restrict__ nbr,
                                                const float* __restrict__ old_z,
                                                const float* __restrict__ tau1,
                                                const float* __restrict__ tau2,
                                                const float* __restrict__ f1,
                                                const float* __restrict__ f2,
                                                const float* __restrict__ params,
                                                float* __restrict__ out_h,
                                                float* __restrict__ out_z, int n) {
    int t = blockIdx.x * 256 + threadIdx.x;
    int node = t >> 5;
    int lane = threadIdx.x & 31;
    if (node >= n) return;
    int k = __builtin_nontemporal_load(nbr + (long)node * DEG + lane);
    float4 acc = make_float4(0.f, 0.f, 0.f, 0.f);
#pragma unroll
    for (int jj = 0; jj < 4; ++jj) {
        uint2 vs[8];
#pragma unroll
        for (int j = 0; j < 8; ++j) {
            int kj = __shfl(k, jj * 8 + j, 32);
            vs[j] = ((const uint2*)(hb + (long)kj * (FDIM / 2)))[lane];
        }
#pragma unroll
        for (int j = 0; j < 8; ++j) {
            acc.x += __uint_as_float(vs[j].x << 16);
            acc.y += __uint_as_float(vs[j].x & 0xffff0000u);
            acc.z += __uint_as_float(vs[j].y << 16);
            acc.w += __uint_as_float(vs[j].y & 0xffff0000u);
        }
    }
    float a = (f1[node] - params[0]) * params[1] - tau1[0];
    float b = (f2[node] - params[2]) * params[3] - tau2[0];
    // sigmoid(-a)*sigmoid(-b) = 1 / ((1+e^a)(1+e^b))
    float z = 1.f / ((1.f + expf(a)) * (1.f + expf(b)));
    float gate = fminf(old_z[node], z);
    // identity from the bf16 table (same 4 features this lane accumulated)
    uint2 hid = ((const uint2*)(hb + (long)node * (FDIM / 2)))[lane];
    nf4 o;
    o.x = __uint_as_float(hid.x << 16)        + gate * fmaxf(acc.x, 0.f);
    o.y = __uint_as_float(hid.x & 0xffff0000u) + gate * fmaxf(acc.y, 0.f);
    o.z = __uint_as_float(hid.y << 16)        + gate * fmaxf(acc.z, 0.f);
    o.w = __uint_as_float(hid.y & 0xffff0000u) + gate * fmaxf(acc.w, 0.f);
    __builtin_nontemporal_store(o, (nf4*)(out_h + (long)node * FDIM) + lane);
    if (lane == 0) __builtin_nontemporal_store(z, out_z + node);
}

extern "C" void kernel_launch(void* const* d_in, const int* in_sizes, int n_in,
                              void* d_out, int out_size, void* d_ws, size_t ws_size,
                              hipStream_t stream) {
    const float* h      = (const float*)d_in[0];
    const float* logits = (const float*)d_in[1];
    const float* old_z  = (const float*)d_in[2];
    const float* tau1   = (const float*)d_in[3];
    const float* tau2   = (const float*)d_in[4];
    const int*   nbr    = (const int*)d_in[5];

    // workspace layout (~13.3 MB)
    char* ws = (char*)d_ws;
    float*         params   = (float*)ws;                  // 4 floats
    float*         partials = (float*)(ws + 64);           // FEAT_NB*4 floats (~25 KB)
    unsigned char* pred8    = (unsigned char*)(ws + 32768); // NN bytes (50 KB)
    float*         f1       = (float*)(ws + 90112);        // NN floats (200 KB)
    float*         f2       = (float*)(ws + 294912);       // NN floats (200 KB)
    unsigned*      hb       = (unsigned*)(ws + 524288);    // NN*FDIM bf16 = 12.8 MB

    float* out_h = (float*)d_out;
    float* out_z = out_h + (long)NN * FDIM;

    k_pre   <<<PRED_NB + CONV_NB, 256, 0, stream>>>(logits, pred8, h, hb);
    k_feats8<<<FEAT_NB, 256, 0, stream>>>(nbr, pred8, f1, f2, partials, NN);
    k_params<<<1, 256, 0, stream>>>(partials, FEAT_NB, params);
    k_agg_bf<<<(NN * DEG + 255) / 256, 256, 0, stream>>>(hb, nbr, old_z, tau1, tau2,
                                                         f1, f2, params, out_h, out_z, NN);
}

// Round 8
// 147.499 us; speedup vs baseline: 1.0292x; 1.0078x over previous
//
#include <hip/hip_runtime.h>
#include <math.h>

#define NN 50000
#define DEG 32
#define FDIM 128
#define NCLS 16
#define LN_EPS 1e-5f
#define CLAMP_MIN 1e-5f

#define PRED_NB 196              // ceil(NN/256)
#define CONV_NB 512
#define NGROUPS (NN * FDIM / 8)  // 800000 groups of 8 floats
#define FEAT_NB 196              // ceil(NN/256), 1 thread/node

// native vector types (HIP float4 is a class — rejected by nontemporal builtins)
typedef float  nf4 __attribute__((ext_vector_type(4)));
typedef unsigned nu4 __attribute__((ext_vector_type(4)));

__device__ inline unsigned bf_rne(float x) {
    unsigned u = __float_as_uint(x);
    u += 0x7fffu + ((u >> 16) & 1u);  // round-to-nearest-even
    return u >> 16;
}

// ---------------- Kernel 1: fused  argmax(logits) (as u8)  +  h->bf16 pack ----------
__global__ __launch_bounds__(256) void k_pre(const float* __restrict__ logits,
                                             unsigned char* __restrict__ pred8,
                                             const float* __restrict__ h,
                                             unsigned* __restrict__ hb) {
    int b = blockIdx.x;
    if (b < PRED_NB) {
        int i = b * 256 + threadIdx.x;
        if (i >= NN) return;
        const nf4* lp = (const nf4*)(logits + (long)i * NCLS);
        float best = -INFINITY;
        int bi = 0;
#pragma unroll
        for (int q = 0; q < 4; ++q) {
            nf4 v = __builtin_nontemporal_load(lp + q);
#pragma unroll
            for (int r = 0; r < 4; ++r) {
                // strict > keeps FIRST max index (matches jnp.argmax)
                if (v[r] > best) { best = v[r]; bi = q * 4 + r; }
            }
        }
        pred8[i] = (unsigned char)bi;
    } else {
        int g0 = (b - PRED_NB) * 256 + threadIdx.x;
        for (int g = g0; g < NGROUPS; g += CONV_NB * 256) {
            const nf4* src = (const nf4*)(h + (long)g * 8);
            nf4 a = __builtin_nontemporal_load(src);
            nf4 c = __builtin_nontemporal_load(src + 1);
            nu4 o;
            o.x = bf_rne(a.x) | (bf_rne(a.y) << 16);
            o.y = bf_rne(a.z) | (bf_rne(a.w) << 16);
            o.z = bf_rne(c.x) | (bf_rne(c.y) << 16);
            o.w = bf_rne(c.z) | (bf_rne(c.w) << 16);
            ((nu4*)hb)[g] = o;  // plain store: hb is the hot table, keep it in L2
        }
    }
}

// ---------------- Kernel 2: f1/f2 with LDS-staged pred table, 1 thread/node --------
// The 50 KB pred8 table is copied into LDS once per block; the 32 random
// lookups/node become ds_read_u8 (~6 cyc throughput) instead of ~200-cyc
// global L2-hit loads.
__global__ __launch_bounds__(256) void k_feats_lds(const int* __restrict__ nbr,
                                                   const unsigned char* __restrict__ pred8,
                                                   float* __restrict__ f1,
                                                   float* __restrict__ f2,
                                                   float* __restrict__ partials, int n) {
    __shared__ unsigned char lp[NN];  // 50000 B < 64 KB static LDS limit
    // cooperative stage: 50000 B = 3125 uint4 (pred8 is 16B-aligned in ws)
    {
        const uint4* s4 = (const uint4*)pred8;
        uint4* d4 = (uint4*)lp;
        for (int i = threadIdx.x; i < 3125; i += 256) d4[i] = s4[i];
    }
    __syncthreads();
    int node = blockIdx.x * 256 + threadIdx.x;
    float v1 = 0.f, v2 = 0.f;
    if (node < n) {
        // histogram of 32 neighbor preds packed 8 bits/class into two u64s
        unsigned long long lo = 0ull, hi = 0ull;
        const int4* np = (const int4*)(nbr + (long)node * DEG);
#pragma unroll
        for (int q = 0; q < 8; ++q) {
            int4 k4 = np[q];
            int ks[4] = {k4.x, k4.y, k4.z, k4.w};
#pragma unroll
            for (int r = 0; r < 4; ++r) {
                int p = lp[ks[r]];
                unsigned long long inc = 1ull << ((p & 7) * 8);
                if (p < 8) lo += inc; else hi += inc;
            }
        }
        int cp = lp[node];
        unsigned long long src = (cp < 8) ? lo : hi;
        v1 = (float)((src >> ((cp & 7) * 8)) & 0xffull);  // f1 = hist[center_pred]
        float ent = 0.f;
#pragma unroll
        for (int c = 0; c < NCLS; ++c) {
            unsigned long long s = (c < 8) ? lo : hi;
            float cnt = (float)((s >> ((c & 7) * 8)) & 0xffull);
            float x = fmaxf(cnt, CLAMP_MIN);  // clipped zeros contribute too
            ent -= x * logf(x);
        }
        v2 = ent;
        f1[node] = v1;
        f2[node] = v2;
    }
    // block-reduce {sum f1, sum f1^2, sum f2, sum f2^2}
    float s0 = v1, s1 = v1 * v1, s2 = v2, s3 = v2 * v2;
#pragma unroll
    for (int off = 32; off > 0; off >>= 1) {  // wave = 64 lanes
        s0 += __shfl_down(s0, off);
        s1 += __shfl_down(s1, off);
        s2 += __shfl_down(s2, off);
        s3 += __shfl_down(s3, off);
    }
    __shared__ float red[4][4];
    int wid = threadIdx.x >> 6;
    if ((threadIdx.x & 63) == 0) {
        red[wid][0] = s0; red[wid][1] = s1; red[wid][2] = s2; red[wid][3] = s3;
    }
    __syncthreads();
    if (threadIdx.x == 0) {
        float t0 = 0.f, t1 = 0.f, t2 = 0.f, t3 = 0.f;
#pragma unroll
        for (int w = 0; w < 4; ++w) {
            t0 += red[w][0]; t1 += red[w][1]; t2 += red[w][2]; t3 += red[w][3];
        }
        float* pp = partials + (long)blockIdx.x * 4;
        pp[0] = t0; pp[1] = t1; pp[2] = t2; pp[3] = t3;
    }
}

// ---------------- Kernel 3: finalize LayerNorm params (1 block) ----------------
__global__ __launch_bounds__(256) void k_params(const float* __restrict__ partials,
                                                int nb, float* __restrict__ params) {
    double s0 = 0, s1 = 0, s2 = 0, s3 = 0;
    for (int b = threadIdx.x; b < nb; b += 256) {
        const float* pp = partials + (long)b * 4;
        s0 += (double)pp[0]; s1 += (double)pp[1];
        s2 += (double)pp[2]; s3 += (double)pp[3];
    }
#pragma unroll
    for (int off = 32; off > 0; off >>= 1) {
        s0 += __shfl_down(s0, off);
        s1 += __shfl_down(s1, off);
        s2 += __shfl_down(s2, off);
        s3 += __shfl_down(s3, off);
    }
    __shared__ double red[4][4];
    int wid = threadIdx.x >> 6;
    if ((threadIdx.x & 63) == 0) {
        red[wid][0] = s0; red[wid][1] = s1; red[wid][2] = s2; red[wid][3] = s3;
    }
    __syncthreads();
    if (threadIdx.x == 0) {
        double t0 = 0, t1 = 0, t2 = 0, t3 = 0;
        for (int w = 0; w < 4; ++w) {
            t0 += red[w][0]; t1 += red[w][1]; t2 += red[w][2]; t3 += red[w][3];
        }
        double inv_n = 1.0 / (double)NN;
        double m1 = t0 * inv_n;
        double var1 = t1 * inv_n - m1 * m1;  // biased var, matches jnp.var
        double m2 = t2 * inv_n;
        double var2 = t3 * inv_n - m2 * m2;
        params[0] = (float)m1;
        params[1] = (float)(1.0 / sqrt(var1 + (double)LN_EPS));
        params[2] = (float)m2;
        params[3] = (float)(1.0 / sqrt(var2 + (double)LN_EPS));
    }
}

// ---------------- Kernel 4 (bf16 gather): z/gate + neighbor aggregation ----------------
// MEASURED 46.8 us / 147.5 MB FETCH (R7) — frozen. 32 lanes/node, lane = one
// uint2 (4 bf16) -> contiguous 256B row per gather; identity also from hb.
__global__ __launch_bounds__(256) void k_agg_bf(const unsigned* __restrict__ hb,
                                                const int* __restrict__ nbr,
                                                const float* __restrict__ old_z,
                                                const float* __restrict__ tau1,
                                                const float* __restrict__ tau2,
                                                const float* __restrict__ f1,
                                                const float* __restrict__ f2,
                                                const float* __restrict__ params,
                                                float* __restrict__ out_h,
                                                float* __restrict__ out_z, int n) {
    int t = blockIdx.x * 256 + threadIdx.x;
    int node = t >> 5;
    int lane = threadIdx.x & 31;
    if (node >= n) return;
    int k = __builtin_nontemporal_load(nbr + (long)node * DEG + lane);
    float4 acc = make_float4(0.f, 0.f, 0.f, 0.f);
#pragma unroll
    for (int jj = 0; jj < 4; ++jj) {
        uint2 vs[8];
#pragma unroll
        for (int j = 0; j < 8; ++j) {
            int kj = __shfl(k, jj * 8 + j, 32);
            vs[j] = ((const uint2*)(hb + (long)kj * (FDIM / 2)))[lane];
        }
#pragma unroll
        for (int j = 0; j < 8; ++j) {
            acc.x += __uint_as_float(vs[j].x << 16);
            acc.y += __uint_as_float(vs[j].x & 0xffff0000u);
            acc.z += __uint_as_float(vs[j].y << 16);
            acc.w += __uint_as_float(vs[j].y & 0xffff0000u);
        }
    }
    float a = (f1[node] - params[0]) * params[1] - tau1[0];
    float b = (f2[node] - params[2]) * params[3] - tau2[0];
    // sigmoid(-a)*sigmoid(-b) = 1 / ((1+e^a)(1+e^b))
    float z = 1.f / ((1.f + expf(a)) * (1.f + expf(b)));
    float gate = fminf(old_z[node], z);
    // identity from the bf16 table (same 4 features this lane accumulated)
    uint2 hid = ((const uint2*)(hb + (long)node * (FDIM / 2)))[lane];
    nf4 o;
    o.x = __uint_as_float(hid.x << 16)         + gate * fmaxf(acc.x, 0.f);
    o.y = __uint_as_float(hid.x & 0xffff0000u) + gate * fmaxf(acc.y, 0.f);
    o.z = __uint_as_float(hid.y << 16)         + gate * fmaxf(acc.z, 0.f);
    o.w = __uint_as_float(hid.y & 0xffff0000u) + gate * fmaxf(acc.w, 0.f);
    __builtin_nontemporal_store(o, (nf4*)(out_h + (long)node * FDIM) + lane);
    if (lane == 0) __builtin_nontemporal_store(z, out_z + node);
}

extern "C" void kernel_launch(void* const* d_in, const int* in_sizes, int n_in,
                              void* d_out, int out_size, void* d_ws, size_t ws_size,
                              hipStream_t stream) {
    const float* h      = (const float*)d_in[0];
    const float* logits = (const float*)d_in[1];
    const float* old_z  = (const float*)d_in[2];
    const float* tau1   = (const float*)d_in[3];
    const float* tau2   = (const float*)d_in[4];
    const int*   nbr    = (const int*)d_in[5];

    // workspace layout (~13.3 MB)
    char* ws = (char*)d_ws;
    float*         params   = (float*)ws;                   // 4 floats
    float*         partials = (float*)(ws + 64);            // FEAT_NB*4 floats
    unsigned char* pred8    = (unsigned char*)(ws + 32768); // NN bytes (50 KB, 16B-aligned)
    float*         f1       = (float*)(ws + 90112);         // NN floats (200 KB)
    float*         f2       = (float*)(ws + 294912);        // NN floats (200 KB)
    unsigned*      hb       = (unsigned*)(ws + 524288);     // NN*FDIM bf16 = 12.8 MB

    float* out_h = (float*)d_out;
    float* out_z = out_h + (long)NN * FDIM;

    k_pre     <<<PRED_NB + CONV_NB, 256, 0, stream>>>(logits, pred8, h, hb);
    k_feats_lds<<<FEAT_NB, 256, 0, stream>>>(nbr, pred8, f1, f2, partials, NN);
    k_params  <<<1, 256, 0, stream>>>(partials, FEAT_NB, params);
    k_agg_bf  <<<(NN * DEG + 255) / 256, 256, 0, stream>>>(hb, nbr, old_z, tau1, tau2,
                                                           f1, f2, params, out_h, out_z, NN);
}